// Round 1
// baseline (794.827 us; speedup 1.0000x reference)
//
#include <hip/hip_runtime.h>
#include <hip/hip_bf16.h>

#define N_NODES 50000
#define N_EDGES 800000
#define N_RELS  8
#define FEATS   128

typedef __attribute__((ext_vector_type(8))) short bf16x8;
typedef __attribute__((ext_vector_type(4))) float f32x4;

__device__ __forceinline__ unsigned short f2b(float f) {
    unsigned int u = __float_as_uint(f);
    u += 0x7fffu + ((u >> 16) & 1u);
    return (unsigned short)(u >> 16);
}
__device__ __forceinline__ float b2f(unsigned short b) {
    return __uint_as_float(((unsigned int)b) << 16);
}

// ---- convert h (fp32 -> bf16), 4 elems/thread ----
__global__ void cvt_h_kernel(const float* __restrict__ h, unsigned short* __restrict__ hb) {
    int i = blockIdx.x * 256 + threadIdx.x;          // 1,600,000 float4 chunks
    float4 v = ((const float4*)h)[i];
    ushort4 o;
    o.x = f2b(v.x); o.y = f2b(v.y); o.z = f2b(v.z); o.w = f2b(v.w);
    ((ushort4*)hb)[i] = o;
}

// ---- convert + transpose W: w[r][k][o] -> wt[r][o][k] bf16 ----
__global__ void cvt_w_kernel(const float* __restrict__ w, unsigned short* __restrict__ wt) {
    int idx = blockIdx.x * 256 + threadIdx.x;        // 131072
    int r = idx >> 14;
    int k = (idx >> 7) & 127;
    int o = idx & 127;
    wt[(r << 14) + o * 128 + k] = f2b(w[idx]);
}

// ---- batched GEMM: ht[n][r][o] = sum_k h[n][k] * w[r][k][o], bf16 MFMA ----
// block: 256 thr (4 waves), tile 64 rows x 128 cols, K=128 in 4 steps of 32
__global__ __launch_bounds__(256) void gemm_kernel(const unsigned short* __restrict__ hb,
                                                   const unsigned short* __restrict__ wt,
                                                   unsigned short* __restrict__ ht) {
    __shared__ unsigned short As[64 * 136];    // +8 pad: bank-conflict-free b128 reads
    __shared__ unsigned short Bs[128 * 136];
    const int r  = blockIdx.y;
    const int n0 = blockIdx.x * 64;
    const int tid = threadIdx.x;

    // stage A tile: 64x128 bf16, 16B chunks
    #pragma unroll
    for (int i = 0; i < 4; ++i) {
        int idx = tid + i * 256;                 // 0..1023, 16 chunks/row
        int row = idx >> 4, ck = idx & 15;
        int n = n0 + row;
        uint4 v = make_uint4(0u, 0u, 0u, 0u);
        if (n < N_NODES) v = *(const uint4*)&hb[(size_t)n * 128 + ck * 8];
        *(uint4*)&As[row * 136 + ck * 8] = v;
    }
    // stage B tile: Wt[r] 128x128 (already [o][k] layout)
    const unsigned short* wtr = wt + ((size_t)r << 14);
    #pragma unroll
    for (int i = 0; i < 8; ++i) {
        int idx = tid + i * 256;                 // 0..2047
        int row = idx >> 4, ck = idx & 15;
        uint4 v = *(const uint4*)&wtr[row * 128 + ck * 8];
        *(uint4*)&Bs[row * 136 + ck * 8] = v;
    }
    __syncthreads();

    const int wave = tid >> 6;
    const int lane = tid & 63;
    const int m16  = lane & 15;
    const int quad = lane >> 4;

    f32x4 acc[8];
    #pragma unroll
    for (int t = 0; t < 8; ++t) acc[t] = (f32x4){0.f, 0.f, 0.f, 0.f};

    #pragma unroll
    for (int kk = 0; kk < 4; ++kk) {
        bf16x8 a = *(const bf16x8*)&As[(wave * 16 + m16) * 136 + kk * 32 + quad * 8];
        #pragma unroll
        for (int t = 0; t < 8; ++t) {
            bf16x8 b = *(const bf16x8*)&Bs[(t * 16 + m16) * 136 + kk * 32 + quad * 8];
            acc[t] = __builtin_amdgcn_mfma_f32_16x16x32_bf16(a, b, acc[t], 0, 0, 0);
        }
    }

    // epilogue: C/D layout col=lane&15, row=quad*4+reg  [measured m89]
    #pragma unroll
    for (int t = 0; t < 8; ++t) {
        #pragma unroll
        for (int reg = 0; reg < 4; ++reg) {
            int n = n0 + wave * 16 + quad * 4 + reg;
            if (n < N_NODES) {
                int o = t * 16 + m16;
                ht[(size_t)n * (N_RELS * 128) + r * 128 + o] = f2b(acc[t][reg]);
            }
        }
    }
}

// ---- edge scatter: one wave per edge, 2 outputs/lane, fp32 atomics ----
__global__ __launch_bounds__(256) void edge_kernel(const unsigned short* __restrict__ ht,
                                                   const float* __restrict__ en,
                                                   const int* __restrict__ et,
                                                   const int* __restrict__ src,
                                                   const int* __restrict__ dst,
                                                   float* __restrict__ acc) {
    int e = blockIdx.x * 4 + (threadIdx.x >> 6);
    if (e >= N_EDGES) return;
    int lane = threadIdx.x & 63;
    int t = et[e], s = src[e], d = dst[e];
    float w = en[e];
    unsigned int v = *(const unsigned int*)&ht[(size_t)s * (N_RELS * 128) + t * 128 + lane * 2];
    float f0 = b2f((unsigned short)(v & 0xffffu)) * w;
    float f1 = b2f((unsigned short)(v >> 16)) * w;
    float* p = &acc[(size_t)d * 128 + lane * 2];
    atomicAdd(p, f0);
    atomicAdd(p + 1, f1);
}

// ---- bias + relu ----
__global__ void bias_relu_kernel(const float* __restrict__ acc, const float* __restrict__ bias,
                                 float* __restrict__ out) {
    int i = blockIdx.x * 256 + threadIdx.x;          // 1,600,000 float4 chunks
    float4 a = ((const float4*)acc)[i];
    float4 b = ((const float4*)bias)[i & 31];        // 32 float4 per 128-col row
    float4 o;
    o.x = fmaxf(a.x + b.x, 0.f);
    o.y = fmaxf(a.y + b.y, 0.f);
    o.z = fmaxf(a.z + b.z, 0.f);
    o.w = fmaxf(a.w + b.w, 0.f);
    ((float4*)out)[i] = o;
}

extern "C" void kernel_launch(void* const* d_in, const int* in_sizes, int n_in,
                              void* d_out, int out_size, void* d_ws, size_t ws_size,
                              hipStream_t stream) {
    const float* h    = (const float*)d_in[0];
    const float* en   = (const float*)d_in[1];
    const int*   et   = (const int*)d_in[2];
    const int*   src  = (const int*)d_in[3];
    const int*   dst  = (const int*)d_in[4];
    const float* w    = (const float*)d_in[5];
    const float* bias = (const float*)d_in[6];
    float* out = (float*)d_out;

    char* ws = (char*)d_ws;
    unsigned short* hb = (unsigned short*)(ws);                 // 12,800,000 B
    unsigned short* wt = (unsigned short*)(ws + 12800000);      //    262,144 B
    unsigned short* ht = (unsigned short*)(ws + 13062144);      // 102,400,000 B
    float*          acc = (float*)(ws + 115462144);             //  25,600,000 B

    hipMemsetAsync(acc, 0, (size_t)N_NODES * FEATS * sizeof(float), stream);
    hipLaunchKernelGGL(cvt_h_kernel, dim3(6250), dim3(256), 0, stream, h, hb);
    hipLaunchKernelGGL(cvt_w_kernel, dim3(512), dim3(256), 0, stream, w, wt);
    hipLaunchKernelGGL(gemm_kernel, dim3(782, N_RELS), dim3(256), 0, stream, hb, wt, ht);
    hipLaunchKernelGGL(edge_kernel, dim3(N_EDGES / 4), dim3(256), 0, stream, ht, en, et, src, dst, acc);
    hipLaunchKernelGGL(bias_relu_kernel, dim3(6250), dim3(256), 0, stream, acc, bias, out);
}

// Round 2
// 284.465 us; speedup vs baseline: 2.7941x; 2.7941x over previous
//
#include <hip/hip_runtime.h>
#include <hip/hip_bf16.h>

#define N_NODES 50000
#define N_EDGES 800000
#define N_RELS  8
#define FEATS   128
#define NB_SCAN 196   // ceil(50000/256)

typedef __attribute__((ext_vector_type(8))) short bf16x8;
typedef __attribute__((ext_vector_type(4))) float f32x4;

__device__ __forceinline__ unsigned short f2b(float f) {
    unsigned int u = __float_as_uint(f);
    u += 0x7fffu + ((u >> 16) & 1u);
    return (unsigned short)(u >> 16);
}
__device__ __forceinline__ float b2f(unsigned short b) {
    return __uint_as_float(((unsigned int)b) << 16);
}

// ---- convert h (fp32 -> bf16), 4 elems/thread ----
__global__ void cvt_h_kernel(const float* __restrict__ h, unsigned short* __restrict__ hb) {
    int i = blockIdx.x * 256 + threadIdx.x;
    float4 v = ((const float4*)h)[i];
    ushort4 o;
    o.x = f2b(v.x); o.y = f2b(v.y); o.z = f2b(v.z); o.w = f2b(v.w);
    ((ushort4*)hb)[i] = o;
}

// ---- convert + transpose W: w[r][k][o] -> wt[r][o][k] bf16 ----
__global__ void cvt_w_kernel(const float* __restrict__ w, unsigned short* __restrict__ wt) {
    int idx = blockIdx.x * 256 + threadIdx.x;        // 131072
    int r = idx >> 14;
    int k = (idx >> 7) & 127;
    int o = idx & 127;
    wt[(r << 14) + o * 128 + k] = f2b(w[idx]);
}

// ---- batched GEMM: ht[n][r][o] = sum_k h[n][k] * w[r][k][o], bf16 MFMA ----
__global__ __launch_bounds__(256) void gemm_kernel(const unsigned short* __restrict__ hb,
                                                   const unsigned short* __restrict__ wt,
                                                   unsigned short* __restrict__ ht) {
    __shared__ unsigned short As[64 * 136];
    __shared__ unsigned short Bs[128 * 136];
    const int r  = blockIdx.y;
    const int n0 = blockIdx.x * 64;
    const int tid = threadIdx.x;

    #pragma unroll
    for (int i = 0; i < 4; ++i) {
        int idx = tid + i * 256;
        int row = idx >> 4, ck = idx & 15;
        int n = n0 + row;
        uint4 v = make_uint4(0u, 0u, 0u, 0u);
        if (n < N_NODES) v = *(const uint4*)&hb[(size_t)n * 128 + ck * 8];
        *(uint4*)&As[row * 136 + ck * 8] = v;
    }
    const unsigned short* wtr = wt + ((size_t)r << 14);
    #pragma unroll
    for (int i = 0; i < 8; ++i) {
        int idx = tid + i * 256;
        int row = idx >> 4, ck = idx & 15;
        uint4 v = *(const uint4*)&wtr[row * 128 + ck * 8];
        *(uint4*)&Bs[row * 136 + ck * 8] = v;
    }
    __syncthreads();

    const int wave = tid >> 6;
    const int lane = tid & 63;
    const int m16  = lane & 15;
    const int quad = lane >> 4;

    f32x4 acc[8];
    #pragma unroll
    for (int t = 0; t < 8; ++t) acc[t] = (f32x4){0.f, 0.f, 0.f, 0.f};

    #pragma unroll
    for (int kk = 0; kk < 4; ++kk) {
        bf16x8 a = *(const bf16x8*)&As[(wave * 16 + m16) * 136 + kk * 32 + quad * 8];
        #pragma unroll
        for (int t = 0; t < 8; ++t) {
            bf16x8 b = *(const bf16x8*)&Bs[(t * 16 + m16) * 136 + kk * 32 + quad * 8];
            acc[t] = __builtin_amdgcn_mfma_f32_16x16x32_bf16(a, b, acc[t], 0, 0, 0);
        }
    }

    #pragma unroll
    for (int t = 0; t < 8; ++t) {
        #pragma unroll
        for (int reg = 0; reg < 4; ++reg) {
            int n = n0 + wave * 16 + quad * 4 + reg;
            if (n < N_NODES) {
                int o = t * 16 + m16;
                ht[(size_t)n * (N_RELS * 128) + r * 128 + o] = f2b(acc[t][reg]);
            }
        }
    }
}

// ---- histogram of dst ----
__global__ void hist_kernel(const int* __restrict__ dst, int* __restrict__ counts) {
    int e = blockIdx.x * 256 + threadIdx.x;          // grid exact: 800000/256
    atomicAdd(&counts[dst[e]], 1);
}

// ---- scan phase 1: per-block exclusive scan + block sums ----
__global__ void scan1_kernel(const int* __restrict__ counts, int* __restrict__ partial,
                             int* __restrict__ bsum) {
    __shared__ int tmp[256];
    int i = blockIdx.x * 256 + threadIdx.x;
    int v = (i < N_NODES) ? counts[i] : 0;
    tmp[threadIdx.x] = v;
    __syncthreads();
    #pragma unroll
    for (int off = 1; off < 256; off <<= 1) {
        int t = (threadIdx.x >= off) ? tmp[threadIdx.x - off] : 0;
        __syncthreads();
        tmp[threadIdx.x] += t;
        __syncthreads();
    }
    if (i < N_NODES) partial[i] = tmp[threadIdx.x] - v;   // exclusive
    if (threadIdx.x == 255) bsum[blockIdx.x] = tmp[255];
}

// ---- scan phase 2: exclusive scan of block sums (single block) ----
__global__ void scan2_kernel(int* __restrict__ bsum) {
    __shared__ int tmp[256];
    int i = threadIdx.x;
    int v = (i < NB_SCAN) ? bsum[i] : 0;
    tmp[i] = v;
    __syncthreads();
    #pragma unroll
    for (int off = 1; off < 256; off <<= 1) {
        int t = (i >= off) ? tmp[i - off] : 0;
        __syncthreads();
        tmp[i] += t;
        __syncthreads();
    }
    if (i < NB_SCAN) bsum[i] = tmp[i] - v;
}

// ---- scan phase 3: add block offsets; init row_start + cursor ----
__global__ void scan3_kernel(const int* __restrict__ partial, const int* __restrict__ bsum,
                             int* __restrict__ row_start, int* __restrict__ cursor) {
    int i = blockIdx.x * 256 + threadIdx.x;
    if (i < N_NODES) {
        int rs = partial[i] + bsum[i >> 8];
        row_start[i] = rs;
        cursor[i] = rs;
    }
    if (i == 0) row_start[N_NODES] = N_EDGES;
}

// ---- scatter edges into dst-sorted order ----
__global__ void scatter_kernel(const int* __restrict__ src, const int* __restrict__ dst,
                               const int* __restrict__ et, const float* __restrict__ en,
                               int* __restrict__ cursor, int2* __restrict__ meta) {
    int e = blockIdx.x * 256 + threadIdx.x;
    int d = dst[e];
    int pos = atomicAdd(&cursor[d], 1);
    meta[pos] = make_int2(src[e] | (et[e] << 16), __float_as_int(en[e]));
}

// ---- gather: one wave per dst node, fused bias+relu ----
__global__ __launch_bounds__(256) void gather_kernel(const unsigned short* __restrict__ ht,
                                                     const int2* __restrict__ meta,
                                                     const int* __restrict__ row_start,
                                                     const float* __restrict__ bias,
                                                     float* __restrict__ out) {
    int node = blockIdx.x * 4 + (threadIdx.x >> 6);   // grid 12500 * 4 waves = 50000
    int lane = threadIdx.x & 63;
    int beg = row_start[node], end = row_start[node + 1];
    float a0 = 0.f, a1 = 0.f;
    for (int base = beg; base < end; base += 64) {
        int cnt = end - base; if (cnt > 64) cnt = 64;
        int2 m = make_int2(0, 0);
        if (base + lane < end) m = meta[base + lane];
        #pragma unroll 4
        for (int k = 0; k < cnt; ++k) {
            int p = __shfl(m.x, k);
            float w = __uint_as_float(__shfl(m.y, k));
            int s = p & 0xffff, t = p >> 16;
            unsigned int v = *(const unsigned int*)&ht[((size_t)s << 10) + (t << 7) + lane * 2];
            a0 += b2f((unsigned short)(v & 0xffffu)) * w;
            a1 += b2f((unsigned short)(v >> 16)) * w;
        }
    }
    float b0 = bias[lane * 2], b1 = bias[lane * 2 + 1];
    float2 o = make_float2(fmaxf(a0 + b0, 0.f), fmaxf(a1 + b1, 0.f));
    *(float2*)&out[((size_t)node << 7) + lane * 2] = o;
}

extern "C" void kernel_launch(void* const* d_in, const int* in_sizes, int n_in,
                              void* d_out, int out_size, void* d_ws, size_t ws_size,
                              hipStream_t stream) {
    const float* h    = (const float*)d_in[0];
    const float* en   = (const float*)d_in[1];
    const int*   et   = (const int*)d_in[2];
    const int*   src  = (const int*)d_in[3];
    const int*   dst  = (const int*)d_in[4];
    const float* w    = (const float*)d_in[5];
    const float* bias = (const float*)d_in[6];
    float* out = (float*)d_out;

    char* ws = (char*)d_ws;
    unsigned short* hb  = (unsigned short*)(ws);                 // 12,800,000 B
    unsigned short* wt  = (unsigned short*)(ws + 12800000);      //    262,144 B
    unsigned short* ht  = (unsigned short*)(ws + 13062144);      // 102,400,000 B
    char* sbase = ws + 115462144;
    int*  counts    = (int*)(sbase);                             // 200,704 B slot
    int*  partial   = (int*)(sbase + 200704);
    int*  bsum      = (int*)(sbase + 401408);                    //   1,024 B slot
    int*  row_start = (int*)(sbase + 402432);                    // 200,704 B slot (50001 ints)
    int*  cursor    = (int*)(sbase + 603136);
    int2* meta      = (int2*)(sbase + 803840);                   // 6,400,000 B

    hipMemsetAsync(counts, 0, N_NODES * sizeof(int), stream);
    hipLaunchKernelGGL(cvt_h_kernel, dim3(6250), dim3(256), 0, stream, h, hb);
    hipLaunchKernelGGL(cvt_w_kernel, dim3(512), dim3(256), 0, stream, w, wt);
    hipLaunchKernelGGL(gemm_kernel, dim3(782, N_RELS), dim3(256), 0, stream, hb, wt, ht);
    hipLaunchKernelGGL(hist_kernel, dim3(N_EDGES / 256), dim3(256), 0, stream, dst, counts);
    hipLaunchKernelGGL(scan1_kernel, dim3(NB_SCAN), dim3(256), 0, stream, counts, partial, bsum);
    hipLaunchKernelGGL(scan2_kernel, dim3(1), dim3(256), 0, stream, bsum);
    hipLaunchKernelGGL(scan3_kernel, dim3(NB_SCAN), dim3(256), 0, stream, partial, bsum, row_start, cursor);
    hipLaunchKernelGGL(scatter_kernel, dim3(N_EDGES / 256), dim3(256), 0, stream, src, dst, et, en, cursor, meta);
    hipLaunchKernelGGL(gather_kernel, dim3(12500), dim3(256), 0, stream, ht, meta, row_start, bias, out);
}